// Round 1
// baseline (159.803 us; speedup 1.0000x reference)
//
#include <hip/hip_runtime.h>
#include <math.h>

// Problem: B=4, H=16, N=4096, D=128 -> ROWS = B*H = 64 independent scan rows.
static constexpr int ROWS = 64;
static constexpr int NSEQ = 4096;
static constexpr int DIM  = 128;
static constexpr int TCH  = 64;           // chunk length (timesteps)
static constexpr int CPR  = NSEQ / TCH;   // chunks per row = 64
static constexpr int NCH  = ROWS * CPR;   // 4096 chunks total
static constexpr int GPB  = 8;            // 32-lane groups (=chunks) per 256-thread block

// ---------------------------------------------------------------------------
// K1: per 32-lane group, process one chunk of 64 timesteps.
//  - alpha_t = dot(q_t, k_t) over D=128 (float4 per lane, shfl_xor reduce)
//  - online-rescaled chunk aggregate: M (max alpha), d (sum of exp), n[128]
//  - store alphas (for K3) and aggregates.
// ---------------------------------------------------------------------------
__global__ __launch_bounds__(256) void fla_k1(
    const float* __restrict__ q, const float* __restrict__ k,
    const float* __restrict__ v,
    float* __restrict__ wsAlpha, float* __restrict__ aggM,
    float* __restrict__ aggD, float* __restrict__ aggN)
{
    const int tid  = threadIdx.x;
    const int lane = tid & 31;
    const int g    = blockIdx.x * GPB + (tid >> 5);   // global chunk id
    const int base = g * TCH * DIM;                   // element offset (fits in int)

    float m_cur = -INFINITY;
    float d_run = 0.0f;
    float4 acc  = make_float4(0.f, 0.f, 0.f, 0.f);
    float a0 = 0.f, a1 = 0.f;   // alpha values kept for coalesced writeback

    for (int t = 0; t < TCH; ++t) {
        const float4 q4 = *((const float4*)(q + base + t * DIM) + lane);
        const float4 k4 = *((const float4*)(k + base + t * DIM) + lane);
        float s = q4.x * k4.x + q4.y * k4.y + q4.z * k4.z + q4.w * k4.w;
        // reduce across the 32-lane group (masks <=16 stay within the half-wave)
        s += __shfl_xor(s, 16);
        s += __shfl_xor(s, 8);
        s += __shfl_xor(s, 4);
        s += __shfl_xor(s, 2);
        s += __shfl_xor(s, 1);
        // keep alpha for writeback: lane l holds t==l and t==32+l
        a0 = (t == lane)      ? s : a0;
        a1 = (t == lane + 32) ? s : a1;
        // branchless online-softmax rescale (uniform within the group)
        const float m_new = fmaxf(m_cur, s);
        const float f = __expf(m_cur - m_new);   // exp(-inf)=0 handles first step
        const float w = __expf(s - m_new);
        d_run = d_run * f + w;
        const float4 v4 = *((const float4*)(v + base + t * DIM) + lane);
        acc.x = acc.x * f + w * v4.x;
        acc.y = acc.y * f + w * v4.y;
        acc.z = acc.z * f + w * v4.z;
        acc.w = acc.w * f + w * v4.w;
        m_cur = m_new;
    }

    // alphas: coalesced 2 dwords per lane
    wsAlpha[g * TCH + lane]      = a0;
    wsAlpha[g * TCH + 32 + lane] = a1;
    if (lane == 0) { aggM[g] = m_cur; aggD[g] = d_run; }
    *((float4*)(aggN + g * DIM) + lane) = acc;   // lane owns dims [4*lane, 4*lane+4)
}

// ---------------------------------------------------------------------------
// K2: per row, sequential scan over the CPR chunk aggregates; writes the
// EXCLUSIVE prefix (m_p, d_p, n_p[128]) for every chunk. 64 blocks x 128 thr.
// ---------------------------------------------------------------------------
__global__ __launch_bounds__(128) void fla_k2(
    const float* __restrict__ aggM, const float* __restrict__ aggD,
    const float* __restrict__ aggN,
    float* __restrict__ preM, float* __restrict__ preD, float* __restrict__ preN)
{
    const int r = blockIdx.x;
    const int d = threadIdx.x;
    float m = -INFINITY, dd = 0.f, n = 0.f;
    for (int c = 0; c < CPR; ++c) {
        const int g = r * CPR + c;
        if (d == 0) { preM[g] = m; preD[g] = dd; }
        preN[g * DIM + d] = n;
        const float Mc = aggM[g];
        const float Dc = aggD[g];
        const float nc = aggN[g * DIM + d];
        const float mn = fmaxf(m, Mc);
        const float f1 = __expf(m - mn);     // 0 when m=-inf
        const float f2 = __expf(Mc - mn);
        dd = dd * f1 + Dc * f2;
        n  = n  * f1 + nc * f2;
        m  = mn;
    }
}

// ---------------------------------------------------------------------------
// K3: per 32-lane group, replay one chunk seeded with the exclusive prefix;
// write y_t = n_t / d_t. Alphas come from ws (preloaded, shfl-broadcast).
// ---------------------------------------------------------------------------
__global__ __launch_bounds__(256) void fla_k3(
    const float* __restrict__ v, const float* __restrict__ wsAlpha,
    const float* __restrict__ preM, const float* __restrict__ preD,
    const float* __restrict__ preN, float* __restrict__ y)
{
    const int tid  = threadIdx.x;
    const int lane = tid & 31;
    const int g    = blockIdx.x * GPB + (tid >> 5);
    const int base = g * TCH * DIM;

    const float a0 = wsAlpha[g * TCH + lane];
    const float a1 = wsAlpha[g * TCH + 32 + lane];
    float m_cur = preM[g];               // uniform across group (same address)
    float d_run = preD[g];
    float4 acc  = *((const float4*)(preN + g * DIM) + lane);

    for (int t = 0; t < TCH; ++t) {
        const float s = __shfl((t & 32) ? a1 : a0, t & 31, 32);
        const float m_new = fmaxf(m_cur, s);
        const float f = __expf(m_cur - m_new);
        const float w = __expf(s - m_new);
        d_run = d_run * f + w;
        const float4 v4 = *((const float4*)(v + base + t * DIM) + lane);
        acc.x = acc.x * f + w * v4.x;
        acc.y = acc.y * f + w * v4.y;
        acc.z = acc.z * f + w * v4.z;
        acc.w = acc.w * f + w * v4.w;
        const float rinv = __builtin_amdgcn_rcpf(d_run);
        float4 y4;
        y4.x = acc.x * rinv;
        y4.y = acc.y * rinv;
        y4.z = acc.z * rinv;
        y4.w = acc.w * rinv;
        *((float4*)(y + base + t * DIM) + lane) = y4;
        m_cur = m_new;
    }
}

// ---------------------------------------------------------------------------
extern "C" void kernel_launch(void* const* d_in, const int* in_sizes, int n_in,
                              void* d_out, int out_size, void* d_ws, size_t ws_size,
                              hipStream_t stream) {
    const float* q = (const float*)d_in[0];
    const float* k = (const float*)d_in[1];
    const float* v = (const float*)d_in[2];
    float* y  = (float*)d_out;
    float* ws = (float*)d_ws;

    // ws layout (floats): alpha | aggM | aggD | aggN | preM | preD | preN
    float* wsAlpha = ws;                          // ROWS*NSEQ     = 262144
    float* aggM    = wsAlpha + ROWS * NSEQ;       // NCH           = 4096
    float* aggD    = aggM + NCH;                  // NCH
    float* aggN    = aggD + NCH;                  // NCH*DIM       = 524288
    float* preM    = aggN + NCH * DIM;            // NCH
    float* preD    = preM + NCH;                  // NCH
    float* preN    = preD + NCH;                  // NCH*DIM
    // total: 1,327,104 floats = 5.3 MB

    fla_k1<<<NCH / GPB, 256, 0, stream>>>(q, k, v, wsAlpha, aggM, aggD, aggN);
    fla_k2<<<ROWS, DIM, 0, stream>>>(aggM, aggD, aggN, preM, preD, preN);
    fla_k3<<<NCH / GPB, 256, 0, stream>>>(v, wsAlpha, preM, preD, preN, y);
}